// Round 6
// baseline (67.343 us; speedup 1.0000x reference)
//
#include <hip/hip_runtime.h>
#include <hip/hip_bf16.h>

// Fused shift/roll/unfold/conv (f32 in/out, bf16 LDS intermediate):
//   r[h,k,o,l] = gate_b(k,o)*x[l,h,widx_b(k,o)] + gate_a(k,o)*x[128+l,h,widx_a(k,o)]
//   y[i,n,o]   = sum_{j,k,l} r[n+j-1,k,o,l] * w[i,j,k,l]
//
// Grid (14 n, 16 ig) = 224 blocks (single block-round). Block 512 (8 waves), 16 i/block.
// 1a: COALESCED x[:, n-1..n+1, :] -> xs[256][43] (exact 43KB fetch, conflict-free stride).
// 1b: thread=(j,l): xs rows -> regs -> 42 static-index r values -> rs (bf16).
// 2:  q-split across lanes (q = qi*256+lane*4, tail 1024+lane*2); w in registers.
// 3:  224 thr = 224 outputs, float4 partial reduce.
// xs and parts are unioned (xs dead after the 1b barrier).

__device__ __forceinline__ float bf2f(unsigned short u) {
    union { unsigned int i; float f; } c; c.i = ((unsigned int)u) << 16; return c.f;
}
__device__ __forceinline__ unsigned short f2bf(float f) {
    __hip_bfloat16 b = __float2bfloat16(f);   // RNE
    return *(unsigned short*)&b;
}

#define XSTRIDE 43   // xs row stride: bank(l*43+s) = (11l+s)%32, full cycle -> conflict-free
#define PSTRIDE 68   // parts row stride: 16B-aligned rows

__global__ __launch_bounds__(512) void fused_shiftconv(
    const float* __restrict__ x,    // (256,14,14)
    const float* __restrict__ w,    // (256,3,3,128): i*1152 + (j*3+k)*128 + l
    float* __restrict__ out)        // (256,14,14)
{
    __shared__ __align__(16) unsigned short rs[126 * 128];      // 32256 B bf16 r-slice
    __shared__ __align__(16) float scratch[224 * PSTRIDE];      // 60928 B: xs (11008 f) then parts

    float* xs    = scratch;          // [256][XSTRIDE], phase 1 only
    float* parts = scratch;          // [224][PSTRIDE], phase 2/3 only

    const int n    = blockIdx.x;
    const int ig   = blockIdx.y;          // 0..15, 16 i per block
    const int t    = threadIdx.x;
    const int lane = t & 63;
    const int wv   = t >> 6;              // 0..7

    // ---- w staging into registers (coalesced, overlaps phase 1a) ----
    const float* wbase = w + (ig * 16 + wv * 2) * 1152;
    float4 wq[2][4];
    float2 wt[2];
    #pragma unroll
    for (int ii = 0; ii < 2; ++ii) {
        const float* wp = wbase + ii * 1152;
        #pragma unroll
        for (int qi = 0; qi < 4; ++qi)
            wq[ii][qi] = *(const float4*)(wp + qi * 256 + lane * 4);
        wt[ii] = *(const float2*)(wp + 1024 + lane * 2);
    }

    // ---- Phase 1a: coalesced stage x[:, n-1..n+1, :] -> xs (0 for OOB h) ----
    #pragma unroll
    for (int m = t; m < 256 * 42; m += 512) {     // 21 iters/thread, consecutive addrs in-wave
        const int c  = m / 42;
        const int s  = m - c * 42;
        const int jj = s / 14;
        const int wi = s - jj * 14;
        const int h  = n - 1 + jj;
        float v = 0.f;
        if ((unsigned)h < 14u) v = x[c * 196 + h * 14 + wi];
        xs[c * XSTRIDE + s] = v;
    }
    __syncthreads();

    // ---- Phase 1b: build rs from xs (384 threads; thread = (j = t>>7, l = t&127)) ----
    if (t < 384) {
        const int j = t >> 7;
        const int l = t & 127;
        float xlo[14], xhi[14];
        const float* p0 = xs + l * XSTRIDE + j * 14;
        const float* p1 = xs + (128 + l) * XSTRIDE + j * 14;
        #pragma unroll
        for (int wi = 0; wi < 14; ++wi) { xlo[wi] = p0[wi]; xhi[wi] = p1[wi]; }
        // 42 (k,o) values, all indices compile-time after unroll
        #pragma unroll
        for (int k = 0; k < 3; ++k) {
            #pragma unroll
            for (int o = 0; o < 14; ++o) {
                float val = 0.f;
                const int wb = o + k - 1;                 // B-term gate/index
                if (wb >= 0 && wb < 14) val += xlo[wb ? wb - 1 : 13];
                const int v  = o ? o - 1 : 13;            // A-term gate/index
                const int wa = v + k - 1;
                if (wa >= 0 && wa < 14) val += xhi[wa ? wa - 1 : 13];
                rs[((j * 3 + k) * 14 + o) * 128 + l] = f2bf(val);
            }
        }
    }
    __syncthreads();   // also separates xs reads from parts writes (aliased buffer)

    // ---- Phase 2: per o, per-lane partial dots (18 q per lane, 2 i per wave) ----
    const int rbl   = (lane & 31) * 4;     // l base for qi chunks
    const int jkhi  = lane >> 5;           // 0/1: jk = qi*2 + jkhi
    const int prow0 = wv * 28;             // partial row base (stride PSTRIDE)
    #pragma unroll 2
    for (int o = 0; o < 14; ++o) {
        float rv[18];
        #pragma unroll
        for (int qi = 0; qi < 4; ++qi) {
            const int row = (qi * 2 + jkhi) * 14 + o;
            ushort4 u = *(const ushort4*)(rs + row * 128 + rbl);   // ds_read_b64
            rv[qi * 4 + 0] = bf2f(u.x);
            rv[qi * 4 + 1] = bf2f(u.y);
            rv[qi * 4 + 2] = bf2f(u.z);
            rv[qi * 4 + 3] = bf2f(u.w);
        }
        {
            const int rowt = 112 + o;
            ushort2 ut = *(const ushort2*)(rs + rowt * 128 + lane * 2);
            rv[16] = bf2f(ut.x);
            rv[17] = bf2f(ut.y);
        }
        #pragma unroll
        for (int ii = 0; ii < 2; ++ii) {
            float a;
            a  = rv[0]  * wq[ii][0].x + rv[1]  * wq[ii][0].y + rv[2]  * wq[ii][0].z + rv[3]  * wq[ii][0].w;
            a += rv[4]  * wq[ii][1].x + rv[5]  * wq[ii][1].y + rv[6]  * wq[ii][1].z + rv[7]  * wq[ii][1].w;
            a += rv[8]  * wq[ii][2].x + rv[9]  * wq[ii][2].y + rv[10] * wq[ii][2].z + rv[11] * wq[ii][2].w;
            a += rv[12] * wq[ii][3].x + rv[13] * wq[ii][3].y + rv[14] * wq[ii][3].z + rv[15] * wq[ii][3].w;
            a += rv[16] * wt[ii].x + rv[17] * wt[ii].y;
            parts[(prow0 + ii * 14 + o) * PSTRIDE + lane] = a;
        }
    }
    __syncthreads();

    // ---- Phase 3: reduce 64 lane-partials per output (224 threads = 224 outputs) ----
    if (t < 224) {
        const float* pr = parts + t * PSTRIDE;   // 272-byte row offset: 16B-aligned
        float s0 = 0.f, s1 = 0.f;
        #pragma unroll
        for (int k2 = 0; k2 < 16; k2 += 2) {
            float4 v0 = *(const float4*)(pr + k2 * 4);
            float4 v1 = *(const float4*)(pr + k2 * 4 + 4);
            s0 += v0.x + v0.y + v0.z + v0.w;
            s1 += v1.x + v1.y + v1.z + v1.w;
        }
        const int wv2 = t / 28;
        const int rem = t - wv2 * 28;
        const int ii  = rem / 14;
        const int o   = rem - ii * 14;
        const int i   = ig * 16 + wv2 * 2 + ii;
        out[(i * 14 + n) * 14 + o] = s0 + s1;
    }
}

extern "C" void kernel_launch(void* const* d_in, const int* in_sizes, int n_in,
                              void* d_out, int out_size, void* d_ws, size_t ws_size,
                              hipStream_t stream) {
    const float* x = (const float*)d_in[0];  // 256*14*14
    const float* w = (const float*)d_in[1];  // 256*3*3*128
    float* out = (float*)d_out;              // 256*14*14
    dim3 grid(14, 16);
    fused_shiftconv<<<grid, 512, 0, stream>>>(x, w, out);
}

// Round 7
// 60.652 us; speedup vs baseline: 1.1103x; 1.1103x over previous
//
#include <hip/hip_runtime.h>
#include <hip/hip_bf16.h>

// Fused shift/roll/unfold/conv (all f32, f32 LDS intermediates):
//   r[h,k,o,l] = gate_b(k,o)*x[l,h,widx_b(k,o)] + gate_a(k,o)*x[128+l,h,widx_a(k,o)]
//   y[i,n,o]   = sum_{j,k,l} r[n+j-1,k,o,l] * w[i,j,k,l]
//
// Grid (14 n, 16 ig) = 224 blocks (single round). Block 512 (8 waves), 16 i/block, 2 i/wave.
// Phase 1 (384 thr): thread=(j,l): x rows (global, L2-resident) -> regs -> 42 static r -> rs f32.
// Phase 2: q-split across lanes (q = qi*256+lane*4, tail 1024+lane*2); w in registers.
//          parts row stride 64 with 4-float rotation p=(e+4*row)&63 -> conflict-min both ways.
// Phase 3 (224 thr = 224 outputs): float4 reduce at minimum 8 words/bank.

#define PSTR 64

__global__ __launch_bounds__(512) void fused_shiftconv(
    const float* __restrict__ x,    // (256,14,14)
    const float* __restrict__ w,    // (256,3,3,128): i*1152 + (j*3+k)*128 + l
    float* __restrict__ out)        // (256,14,14)
{
    __shared__ __align__(16) float rs[126 * 128];      // 64512 B f32 r-slice
    __shared__ __align__(16) float parts[224 * PSTR];  // 57344 B rotated lane-partials

    const int n    = blockIdx.x;
    const int ig   = blockIdx.y;          // 0..15, 16 i per block
    const int t    = threadIdx.x;
    const int lane = t & 63;
    const int wv   = t >> 6;              // 0..7

    // ---- w staging into registers (coalesced, overlaps phase 1) ----
    const float* wbase = w + (ig * 16 + wv * 2) * 1152;
    float4 wq[2][4];
    float2 wt[2];
    #pragma unroll
    for (int ii = 0; ii < 2; ++ii) {
        const float* wp = wbase + ii * 1152;
        #pragma unroll
        for (int qi = 0; qi < 4; ++qi)
            wq[ii][qi] = *(const float4*)(wp + qi * 256 + lane * 4);
        wt[ii] = *(const float2*)(wp + 1024 + lane * 2);
    }

    // ---- Phase 1: build rs (384 threads; thread = (j = t>>7, l = t&127)) ----
    if (t < 384) {
        const int j = t >> 7;
        const int l = t & 127;
        const int h = n + j - 1;
        float xlo[14], xhi[14];
        if ((unsigned)h < 14u) {                    // wave-uniform branch
            const float* p0 = x + l * 196 + h * 14;
            const float* p1 = x + (128 + l) * 196 + h * 14;
            #pragma unroll
            for (int wi = 0; wi < 14; wi += 2) {
                float2 a = *(const float2*)(p0 + wi);
                float2 b = *(const float2*)(p1 + wi);
                xlo[wi] = a.x; xlo[wi + 1] = a.y;
                xhi[wi] = b.x; xhi[wi + 1] = b.y;
            }
        } else {
            #pragma unroll
            for (int wi = 0; wi < 14; ++wi) { xlo[wi] = 0.f; xhi[wi] = 0.f; }
        }
        // 42 (k,o) values, all indices compile-time after unroll
        #pragma unroll
        for (int k = 0; k < 3; ++k) {
            #pragma unroll
            for (int o = 0; o < 14; ++o) {
                float val = 0.f;
                const int wb = o + k - 1;                 // B-term gate/index
                if (wb >= 0 && wb < 14) val += xlo[wb ? wb - 1 : 13];
                const int v  = o ? o - 1 : 13;            // A-term gate/index
                const int wa = v + k - 1;
                if (wa >= 0 && wa < 14) val += xhi[wa ? wa - 1 : 13];
                rs[((j * 3 + k) * 14 + o) * 128 + l] = val;
            }
        }
    }
    __syncthreads();

    // ---- Phase 2: per o, per-lane partial dots (18 q per lane, 2 i per wave) ----
    const int rbl   = (lane & 31) * 4;     // l base for qi chunks
    const int jkhi  = lane >> 5;           // 0/1: jk = qi*2 + jkhi
    const int prow0 = wv * 28;             // partial row base
    #pragma unroll 2
    for (int o = 0; o < 14; ++o) {
        const int ro = o * 128;
        float4 rv0 = *(const float4*)(rs + ((0 * 2 + jkhi) * 14) * 128 + ro + rbl);
        float4 rv1 = *(const float4*)(rs + ((1 * 2 + jkhi) * 14) * 128 + ro + rbl);
        float4 rv2 = *(const float4*)(rs + ((2 * 2 + jkhi) * 14) * 128 + ro + rbl);
        float4 rv3 = *(const float4*)(rs + ((3 * 2 + jkhi) * 14) * 128 + ro + rbl);
        float2 rt  = *(const float2*)(rs + (112 + o) * 128 + lane * 2);
        #pragma unroll
        for (int ii = 0; ii < 2; ++ii) {
            float a0, a1;
            a0  = rv0.x * wq[ii][0].x + rv0.y * wq[ii][0].y + rv0.z * wq[ii][0].z + rv0.w * wq[ii][0].w;
            a1  = rv1.x * wq[ii][1].x + rv1.y * wq[ii][1].y + rv1.z * wq[ii][1].z + rv1.w * wq[ii][1].w;
            a0 += rv2.x * wq[ii][2].x + rv2.y * wq[ii][2].y + rv2.z * wq[ii][2].z + rv2.w * wq[ii][2].w;
            a1 += rv3.x * wq[ii][3].x + rv3.y * wq[ii][3].y + rv3.z * wq[ii][3].z + rv3.w * wq[ii][3].w;
            a0 += rt.x * wt[ii].x + rt.y * wt[ii].y;
            const int row = prow0 + ii * 14 + o;
            parts[row * PSTR + ((lane + 4 * row) & 63)] = a0 + a1;   // rotated: conflict-free
        }
    }
    __syncthreads();

    // ---- Phase 3: reduce 64 rotated lane-partials per output (224 thr = 224 outputs) ----
    if (t < 224) {
        const float* pr = parts + t * PSTR;
        float s0 = 0.f, s1 = 0.f;
        #pragma unroll
        for (int g = 0; g < 16; g += 2) {
            float4 v0 = *(const float4*)(pr + ((4 * g + 4 * t) & 63));        // min 8 words/bank
            float4 v1 = *(const float4*)(pr + ((4 * (g + 1) + 4 * t) & 63));
            s0 += v0.x + v0.y + v0.z + v0.w;
            s1 += v1.x + v1.y + v1.z + v1.w;
        }
        const int wv2 = t / 28;
        const int rem = t - wv2 * 28;
        const int ii  = rem / 14;
        const int o   = rem - ii * 14;
        const int i   = ig * 16 + wv2 * 2 + ii;
        out[(i * 14 + n) * 14 + o] = s0 + s1;
    }
}

extern "C" void kernel_launch(void* const* d_in, const int* in_sizes, int n_in,
                              void* d_out, int out_size, void* d_ws, size_t ws_size,
                              hipStream_t stream) {
    const float* x = (const float*)d_in[0];  // 256*14*14
    const float* w = (const float*)d_in[1];  // 256*3*3*128
    float* out = (float*)d_out;              // 256*14*14
    dim3 grid(14, 16);
    fused_shiftconv<<<grid, 512, 0, stream>>>(x, w, out);
}